// Round 1
// baseline (363.358 us; speedup 1.0000x reference)
//
#include <hip/hip_runtime.h>
#include <hip/hip_bf16.h>

// Problem constants (RelKDAdapter_60284160966709)
#define D_SRC 256
#define D_REL 128

typedef short bf16x8 __attribute__((ext_vector_type(8)));
typedef float f32x4 __attribute__((ext_vector_type(4)));

__device__ __forceinline__ unsigned short f2bf(float f) {
  unsigned u = __float_as_uint(f);
  unsigned r = 0x7FFFu + ((u >> 16) & 1u);
  return (unsigned short)((u + r) >> 16);
}

__device__ __forceinline__ bf16x8 pack8(float4 a, float4 b) {
  bf16x8 o;
  o[0] = (short)f2bf(a.x); o[1] = (short)f2bf(a.y);
  o[2] = (short)f2bf(a.z); o[3] = (short)f2bf(a.w);
  o[4] = (short)f2bf(b.x); o[5] = (short)f2bf(b.y);
  o[6] = (short)f2bf(b.z); o[7] = (short)f2bf(b.w);
  return o;
}

// ---------------- W -> bf16 in MFMA B-fragment order ----------------
// Wfrag layout: [ks (8)][j (8)][lane (64)][8 bf16], 16B per (ks,j,lane) slot.
// Frag semantics (mfma_f32_16x16x32_bf16 B operand): col n = j*16 + (lane&15),
// k = ks*32 + (lane>>4)*8 + m.  Value = bf16(W[k][n]) (W stored [K=256][N=128]).
__global__ __launch_bounds__(256) void convert_wt(
    const float* __restrict__ W, unsigned short* __restrict__ Wfrag) {
  int idx = blockIdx.x * 256 + threadIdx.x;  // 0..4095 (8*8*64)
  int lane = idx & 63;
  int j = (idx >> 6) & 7;
  int ks = idx >> 9;
  int n = j * 16 + (lane & 15);
  int k = ks * 32 + (lane >> 4) * 8;
  bf16x8 o;
#pragma unroll
  for (int m = 0; m < 8; ++m)
    o[m] = (short)f2bf(W[(size_t)(k + m) * D_REL + n]);
  *(bf16x8*)(Wfrag + (size_t)idx * 8) = o;  // 16B store, frag-linear
}

// ---------------- MFMA bf16 GEMM: C = A @ W  (barrier-free, no LDS) ----------------
// 4 waves/block, each wave owns 32 rows x 128 cols. Block = 128 rows.
// A fragments loaded directly from global (row-major matches A-frag layout),
// B fragments read frag-linear from Wfrag (64KB, L2-resident).
#define GBM 128

__global__ __launch_bounds__(256) void gemm_mfma(
    const float* __restrict__ A,            // [M, 256] fp32
    const unsigned short* __restrict__ Wfrag,  // [8][8][64][8] bf16 frag-order
    float* __restrict__ C,                  // [M, 128] fp32 out
    unsigned short* __restrict__ Cbf,       // [M, 128] bf16 copy (may be unused)
    int M, int write_bf) {
  const int t = threadIdx.x;
  const int w = t >> 6;        // wave 0..3
  const int lane = t & 63;
  const int quad = lane >> 4;
  const int l16 = lane & 15;
  const int wrow = blockIdx.x * GBM + w * 32;  // wave's first row

  f32x4 acc[2][8];
#pragma unroll
  for (int i = 0; i < 2; ++i)
#pragma unroll
    for (int j = 0; j < 8; ++j) acc[i][j] = (f32x4)(0.0f);

  const int r0 = wrow + l16;        // row for A-frag tile i=0
  const int r1 = wrow + 16 + l16;   // tile i=1
  const bool v0 = r0 < M;
  const bool v1 = r1 < M;
  const float* a0 = A + (size_t)r0 * D_SRC + quad * 8;
  const float* a1 = A + (size_t)r1 * D_SRC + quad * 8;
  const bf16x8* bbase = (const bf16x8*)Wfrag + lane;  // + (ks*8 + j)*64

  const float4 z4 = make_float4(0.f, 0.f, 0.f, 0.f);

#pragma unroll
  for (int ks = 0; ks < 8; ++ks) {
    // A frags: per lane 32B contiguous from its row (2x float4), k = ks*32 + quad*8
    float4 x0 = v0 ? *(const float4*)(a0 + ks * 32) : z4;
    float4 x1 = v0 ? *(const float4*)(a0 + ks * 32 + 4) : z4;
    float4 y0 = v1 ? *(const float4*)(a1 + ks * 32) : z4;
    float4 y1 = v1 ? *(const float4*)(a1 + ks * 32 + 4) : z4;

    // B frags: 8 coalesced 16B loads, same addresses for every wave -> L2 hits
    bf16x8 bfr[8];
#pragma unroll
    for (int j = 0; j < 8; ++j) bfr[j] = bbase[((size_t)ks * 8 + j) * 64];

    bf16x8 af0 = pack8(x0, x1);
    bf16x8 af1 = pack8(y0, y1);

#pragma unroll
    for (int j = 0; j < 8; ++j) {
      acc[0][j] = __builtin_amdgcn_mfma_f32_16x16x32_bf16(af0, bfr[j], acc[0][j], 0, 0, 0);
      acc[1][j] = __builtin_amdgcn_mfma_f32_16x16x32_bf16(af1, bfr[j], acc[1][j], 0, 0, 0);
    }
  }

  // Epilogue: C/D layout col=lane&15, row=quad*4+reg
#pragma unroll
  for (int i = 0; i < 2; ++i) {
#pragma unroll
    for (int r = 0; r < 4; ++r) {
      int grow = wrow + i * 16 + quad * 4 + r;
      if (grow < M) {
#pragma unroll
        for (int j = 0; j < 8; ++j) {
          int gcol = j * 16 + l16;
          float val = acc[i][j][r];
          C[(size_t)grow * D_REL + gcol] = val;
          if (write_bf) Cbf[(size_t)grow * D_REL + gcol] = f2bf(val);
        }
      }
    }
  }
}

// ---------------- Degree count ----------------
__global__ __launch_bounds__(256) void deg_count(
    const int* __restrict__ edge_row, int E, int* __restrict__ cnt) {
  int i = blockIdx.x * blockDim.x + threadIdx.x;
  if (i < E) atomicAdd(&cnt[edge_row[i]], 1);
}

__global__ __launch_bounds__(256) void deg_finalize(
    const int* __restrict__ cnt, int n,
    float* __restrict__ deg_out, float* __restrict__ inv_deg) {
  int i = blockIdx.x * blockDim.x + threadIdx.x;
  if (i < n) {
    int c = cnt[i];
    float d = (float)(c > 1 ? c : 1);
    deg_out[i] = d;
    inv_deg[i] = 1.0f / d;
  }
}

// ---------------- Exclusive scan of cnt -> row_ptr ----------------
#define SCAN_B 256

__global__ __launch_bounds__(SCAN_B) void scan1(
    const int* __restrict__ cnt, int n,
    int* __restrict__ row_ptr, int* __restrict__ block_sums) {
  __shared__ int s[SCAN_B];
  int i = blockIdx.x * SCAN_B + threadIdx.x;
  int v = (i < n) ? cnt[i] : 0;
  s[threadIdx.x] = v;
  __syncthreads();
#pragma unroll
  for (int off = 1; off < SCAN_B; off <<= 1) {
    int add = (threadIdx.x >= off) ? s[threadIdx.x - off] : 0;
    __syncthreads();
    s[threadIdx.x] += add;
    __syncthreads();
  }
  if (i < n) row_ptr[i] = s[threadIdx.x] - v;
  if (threadIdx.x == SCAN_B - 1) block_sums[blockIdx.x] = s[SCAN_B - 1];
}

__global__ __launch_bounds__(512) void scan2(
    int* __restrict__ block_sums, int nblocks) {
  __shared__ int s[512];
  int v = (threadIdx.x < nblocks) ? block_sums[threadIdx.x] : 0;
  s[threadIdx.x] = v;
  __syncthreads();
#pragma unroll
  for (int off = 1; off < 512; off <<= 1) {
    int add = (threadIdx.x >= off) ? s[threadIdx.x - off] : 0;
    __syncthreads();
    s[threadIdx.x] += add;
    __syncthreads();
  }
  if (threadIdx.x < nblocks) block_sums[threadIdx.x] = s[threadIdx.x] - v;
}

__global__ __launch_bounds__(SCAN_B) void scan3(
    int* __restrict__ row_ptr, const int* __restrict__ block_sums,
    int* __restrict__ cursor, int n, int E) {
  int i = blockIdx.x * SCAN_B + threadIdx.x;
  if (i < n) {
    int v = row_ptr[i] + block_sums[blockIdx.x];
    row_ptr[i] = v;
    cursor[i] = v;
  }
  if (i == 0) row_ptr[n] = E;
}

// ---------------- Scatter edges into CSR order ----------------
__global__ __launch_bounds__(256) void scatter_edges(
    const int* __restrict__ edge_row, const int* __restrict__ edge_col,
    int* __restrict__ cursor, int* __restrict__ sorted_col, int E) {
  int e = blockIdx.x * blockDim.x + threadIdx.x;
  if (e < E) {
    int r = edge_row[e];
    int pos = atomicAdd(&cursor[r], 1);
    sorted_col[pos] = edge_col[e];
  }
}

// ---------------- CSR aggregate (bf16 gather): one wave per dst row ----------------
__global__ __launch_bounds__(256) void aggregate_csr_bf16(
    const int* __restrict__ row_ptr, const int* __restrict__ sorted_col,
    const unsigned short* __restrict__ srcb, const float* __restrict__ inv_deg,
    float* __restrict__ dst, int n) {
  int wave = (blockIdx.x * blockDim.x + threadIdx.x) >> 6;
  int lane = threadIdx.x & 63;
  if (wave >= n) return;
  int beg = row_ptr[wave];
  int end = row_ptr[wave + 1];
  const unsigned short* base = srcb + lane * 2;
  float ax = 0.f, ay = 0.f, bx = 0.f, by = 0.f;
  int e = beg;
  for (; e + 1 < end; e += 2) {
    unsigned u0 = *(const unsigned*)(base + (size_t)sorted_col[e] * D_REL);
    unsigned u1 = *(const unsigned*)(base + (size_t)sorted_col[e + 1] * D_REL);
    ax += __uint_as_float(u0 << 16);
    ay += __uint_as_float(u0 & 0xffff0000u);
    bx += __uint_as_float(u1 << 16);
    by += __uint_as_float(u1 & 0xffff0000u);
  }
  if (e < end) {
    unsigned u0 = *(const unsigned*)(base + (size_t)sorted_col[e] * D_REL);
    ax += __uint_as_float(u0 << 16);
    ay += __uint_as_float(u0 & 0xffff0000u);
  }
  float wgt = inv_deg[wave];
  float2 o;
  o.x = (ax + bx) * wgt;
  o.y = (ay + by) * wgt;
  *(float2*)(dst + (size_t)wave * D_REL + lane * 2) = o;
}

// ---------------- CSR aggregate (fp32 gather fallback) ----------------
__global__ __launch_bounds__(256) void aggregate_csr(
    const int* __restrict__ row_ptr, const int* __restrict__ sorted_col,
    const float* __restrict__ src_proj, const float* __restrict__ inv_deg,
    float* __restrict__ dst, int n) {
  int wave = (blockIdx.x * blockDim.x + threadIdx.x) >> 6;
  int lane = threadIdx.x & 63;
  if (wave >= n) return;
  int beg = row_ptr[wave];
  int end = row_ptr[wave + 1];
  const float* base = src_proj + lane * 2;
  float ax = 0.f, ay = 0.f, bx = 0.f, by = 0.f;
  int e = beg;
  for (; e + 1 < end; e += 2) {
    int c0 = sorted_col[e];
    int c1 = sorted_col[e + 1];
    float2 v0 = *(const float2*)(base + (size_t)c0 * D_REL);
    float2 v1 = *(const float2*)(base + (size_t)c1 * D_REL);
    ax += v0.x; ay += v0.y;
    bx += v1.x; by += v1.y;
  }
  if (e < end) {
    int c0 = sorted_col[e];
    float2 v0 = *(const float2*)(base + (size_t)c0 * D_REL);
    ax += v0.x; ay += v0.y;
  }
  float w = inv_deg[wave];
  float2 o;
  o.x = (ax + bx) * w;
  o.y = (ay + by) * w;
  *(float2*)(dst + (size_t)wave * D_REL + lane * 2) = o;
}

extern "C" void kernel_launch(void* const* d_in, const int* in_sizes, int n_in,
                              void* d_out, int out_size, void* d_ws, size_t ws_size,
                              hipStream_t stream) {
  const float* x_src = (const float*)d_in[0];
  // d_in[1] = x_dst, d_in[3] = W_dst: dead (dst_proj is deleted in reference)
  const float* W_src = (const float*)d_in[2];
  const int* edge_row = (const int*)d_in[4];
  const int* edge_col = (const int*)d_in[5];

  const int M = in_sizes[0] / D_SRC;   // N_SRC = 100000
  const int N = in_sizes[1] / 64;      // N_DST = 100000
  const int E = in_sizes[4];           // 640000

  float* out = (float*)d_out;
  float* out_dst = out;                                  // [N, 128]
  float* out_src_proj = out + (size_t)N * D_REL;         // [M, 128]
  float* out_deg = out_src_proj + (size_t)M * D_REL;     // [N]

  // Workspace layout (256B-aligned slabs)
  char* ws = (char*)d_ws;
  size_t off = 0;
  auto alloc = [&](size_t bytes) {
    char* p = ws + off;
    off = (off + bytes + 255) & ~(size_t)255;
    return p;
  };
  int* cnt        = (int*)alloc((size_t)N * sizeof(int));
  int* row_ptr    = (int*)alloc((size_t)(N + 1) * sizeof(int));
  int* cursor     = (int*)alloc((size_t)N * sizeof(int));
  int* sorted_col = (int*)alloc((size_t)E * sizeof(int));
  float* inv_deg  = (float*)alloc((size_t)N * sizeof(float));
  int* block_sums = (int*)alloc(512 * sizeof(int));
  unsigned short* WT = (unsigned short*)alloc((size_t)D_REL * D_SRC * sizeof(unsigned short));
  size_t base_need = off;
  unsigned short* src_bf = (unsigned short*)alloc((size_t)M * D_REL * sizeof(unsigned short));
  const bool use_bf = (ws_size >= off);
  (void)base_need;

  const int scan_blocks = (N + SCAN_B - 1) / SCAN_B;  // 391 <= 512

  hipMemsetAsync(cnt, 0, (size_t)N * sizeof(int), stream);

  // W bf16, MFMA B-fragment order: 8*8*64 slots of 8 bf16 = 4096 threads
  convert_wt<<<16, 256, 0, stream>>>(W_src, WT);

  // Degree + inv_deg
  deg_count<<<(E + 255) / 256, 256, 0, stream>>>(edge_row, E, cnt);
  deg_finalize<<<(N + 255) / 256, 256, 0, stream>>>(cnt, N, out_deg, inv_deg);

  // Exclusive scan cnt -> row_ptr; cursor = row_ptr
  scan1<<<scan_blocks, SCAN_B, 0, stream>>>(cnt, N, row_ptr, block_sums);
  scan2<<<1, 512, 0, stream>>>(block_sums, scan_blocks);
  scan3<<<scan_blocks, SCAN_B, 0, stream>>>(row_ptr, block_sums, cursor, N, E);

  // CSR scatter
  scatter_edges<<<(E + 255) / 256, 256, 0, stream>>>(edge_row, edge_col, cursor,
                                                     sorted_col, E);

  // MFMA GEMM: src_proj fp32 (+ bf16 copy for the gather if ws allows)
  gemm_mfma<<<(M + GBM - 1) / GBM, 256, 0, stream>>>(
      x_src, WT, out_src_proj, src_bf, M, use_bf ? 1 : 0);

  // Gather-aggregate: 1 wave per dst row, 4 waves per block
  if (use_bf) {
    aggregate_csr_bf16<<<(N + 3) / 4, 256, 0, stream>>>(row_ptr, sorted_col, src_bf,
                                                        inv_deg, out_dst, N);
  } else {
    aggregate_csr<<<(N + 3) / 4, 256, 0, stream>>>(row_ptr, sorted_col, out_src_proj,
                                                   inv_deg, out_dst, N);
  }
}